// Round 22
// baseline (237.243 us; speedup 1.0000x reference)
//
#include <hip/hip_runtime.h>
#include <math.h>

typedef unsigned short ushort_t;
typedef short s16x8 __attribute__((ext_vector_type(8)));
typedef float f32x4 __attribute__((ext_vector_type(4)));

#define MFMA16(a, b, c) __builtin_amdgcn_mfma_f32_16x16x32_bf16(a, b, c, 0, 0, 0)

#define BATCH 4
#define SEQ   1025
#define CH    768
#define HEADS 12
#define NBH   48
#define NKPAD 1088
#define NTILE 17
#define NQB   34          // 1088 / 32 query blocks
#define MROWS 4100
#define SCALE2 0.18033688011112042f   // 0.125 * log2(e)

__device__ __forceinline__ ushort_t f2bf(float f) {
    unsigned u = __builtin_bit_cast(unsigned, f);
    u += 0x7FFFu + ((u >> 16) & 1u);
    return (ushort_t)(u >> 16);
}
__device__ __forceinline__ unsigned cvt_pk_bf16(float lo, float hi) {
    unsigned r;
    asm("v_cvt_pk_bf16_f32 %0, %1, %2" : "=v"(r) : "v"(lo), "v"(hi));
    return r;
}
__device__ __forceinline__ float max3f(float a, float b, float c) {
    float r;
    asm("v_max3_f32 %0, %1, %2, %3" : "=v"(r) : "v"(a), "v"(b), "v"(c));
    return r;
}
__device__ __forceinline__ float fast_exp2(float x) {
    float r; asm("v_exp_f32 %0, %1" : "=v"(r) : "v"(x)); return r;
}

// ================== fused prep: convx + convT(wkv) + convT(wp) + zeropad ==================
__global__ __launch_bounds__(256) void prep(
    const float* __restrict__ x, ushort_t* __restrict__ xb,
    const float* __restrict__ w_qkv, ushort_t* __restrict__ wkvT,
    const float* __restrict__ w_proj, ushort_t* __restrict__ wpT,
    ushort_t* __restrict__ kbuf, ushort_t* __restrict__ vtbuf, ushort_t* __restrict__ qtb)
{
    __shared__ float tile[32][33];
    int b = blockIdx.x, t = threadIdx.x;
    if (b < 3075) {                       // convx: x f32 -> bf16 (787200 float4s)
        int i = b * 256 + t;
        float4 v = ((const float4*)x)[i];
        ushort_t o[4] = {f2bf(v.x), f2bf(v.y), f2bf(v.z), f2bf(v.w)};
        *(uint2*)(xb + (size_t)i * 4) = *(const uint2*)o;
        return;
    }
    const float* src; ushort_t* dst; int ld, c0, k0, n0;
    if (b < 3075 + 1152) {                // convT wkv: dst[n][k]=bf16(w_qkv[k][CH+n])
        int j = b - 3075;
        src = w_qkv; dst = wkvT; ld = 3 * CH; c0 = CH;
        k0 = (j % 24) * 32; n0 = (j / 24) * 32;
    } else if (b < 3075 + 1152 + 576) {   // convT wp
        int j = b - 3075 - 1152;
        src = w_proj; dst = wpT; ld = CH; c0 = 0;
        k0 = (j % 24) * 32; n0 = (j / 24) * 32;
    } else {                              // zeropad (756 blocks x 256 = 193536)
        int i = (b - 4803) * 256 + t;
        {   // kbuf + qtb rows 1025..1087
            int bh = i / (63 * 64), rem = i % (63 * 64);
            kbuf[((size_t)bh * NKPAD + 1025 + rem / 64) * 64 + (rem & 63)] = 0;
            qtb [((size_t)bh * NKPAD + 1025 + rem / 64) * 64 + (rem & 63)] = 0;
        }
        {   // vtb cols 1025..1087
            int bh = i / (64 * 63), rem = i % (64 * 63);
            vtbuf[((size_t)bh * 64 + rem / 63) * NKPAD + 1025 + rem % 63] = 0;
        }
        return;
    }
    int tx = t & 31, ty = t >> 5;
    #pragma unroll
    for (int i = 0; i < 32; i += 8)
        tile[ty + i][tx] = src[(size_t)(k0 + ty + i) * ld + c0 + n0 + tx];
    __syncthreads();
    #pragma unroll
    for (int i = 0; i < 32; i += 8)
        dst[(size_t)(n0 + ty + i) * CH + k0 + tx] = f2bf(tile[tx][ty + i]);
}

// ================== fused GEMMs: fp32 q (8x4 microtile, split-K=2) + bf16 K/V ==================
// 1584 blocks, chunk-8 interleave: cls=(lin>>3)&1 (0=KV MFMA, 1=fp32 VALU),
// xcd=lin&7, cc=lin>>4 (0..98). Per class the mapping is bijective and each
// XCD owns a contiguous logical chunk. fp32 uses 128x64 tiles with an 8x4
// microtile: 1.33 flop/LDS-byte (vs 1.0 at 4x4) — the fused kernel is
// CU-level LDS-BW-bound (r21: VALU 45% vs 53% solo). Per-output k-ascending
// fp32 chain unchanged -> mask bits identical.

__device__ __forceinline__ void fp32_body(char* lds, int bx, int slab,
    const float* __restrict__ A, const float* __restrict__ Bm,
    float* __restrict__ C0, float* __restrict__ C1)
{
    float (*As)[132] = (float(*)[132])lds;                 // [32][132] f32 = 16896 B
    float (*Bs)[68]  = (float(*)[68])(lds + 32 * 132 * 4); // [32][68]  f32 =  8704 B
    const int M = MROWS, K = CH, ldb = 3 * CH, Nn = CH;
    int t = threadIdx.x;
    int m0 = (bx / 12) * 128, n0 = (bx % 12) * 64;
    int kbase = slab * 384;
    float* __restrict__ Cm = slab ? C1 : C0;

    int ty = t >> 4, tx = t & 15;          // 16 row-groups of 8, 16 col-groups of 4
    int laRow = t >> 1, laK = (t & 1) * 16;
    int lbK = t >> 3, lbN = (t & 7) * 8;
    float acc[8][4] = {};
    for (int k0 = kbase; k0 < kbase + 384; k0 += 32) {
        int arow = m0 + laRow;
        #pragma unroll
        for (int i = 0; i < 4; ++i) {
            float4 av = make_float4(0.f, 0.f, 0.f, 0.f);
            if (arow < M) av = *(const float4*)(A + (size_t)arow * K + k0 + laK + 4 * i);
            As[laK + 4 * i + 0][laRow] = av.x;
            As[laK + 4 * i + 1][laRow] = av.y;
            As[laK + 4 * i + 2][laRow] = av.z;
            As[laK + 4 * i + 3][laRow] = av.w;
        }
        #pragma unroll
        for (int i = 0; i < 2; ++i)
            *(float4*)&Bs[lbK][lbN + 4 * i] =
                *(const float4*)(Bm + (size_t)(k0 + lbK) * ldb + n0 + lbN + 4 * i);
        __syncthreads();
        #pragma unroll
        for (int kk = 0; kk < 32; ++kk) {
            float a[8], b[4];
            *(float4*)&a[0] = *(const float4*)&As[kk][ty * 8];
            *(float4*)&a[4] = *(const float4*)&As[kk][ty * 8 + 4];
            *(float4*)&b[0] = *(const float4*)&Bs[kk][tx * 4];
            #pragma unroll
            for (int i = 0; i < 8; ++i)
                #pragma unroll
                for (int j = 0; j < 4; ++j) acc[i][j] += a[i] * b[j];
        }
        __syncthreads();
    }
    #pragma unroll
    for (int i = 0; i < 8; ++i) {
        int row = m0 + ty * 8 + i;
        if (row >= M) continue;
        *(float4*)(Cm + (size_t)row * Nn + n0 + tx * 4) =
            make_float4(acc[i][0], acc[i][1], acc[i][2], acc[i][3]);
    }
}

__device__ __forceinline__ void kv_body(char* lds, int logical,
    const ushort_t* __restrict__ A, const ushort_t* __restrict__ B,
    ushort_t* __restrict__ kbuf, ushort_t* __restrict__ vtbuf)
{
    ushort_t (*As)[40] = (ushort_t(*)[40])lds;
    ushort_t (*Bs)[40] = (ushort_t(*)[40])(lds + 128 * 40 * 2);
    const int NT = 24;
    int t = threadIdx.x, w = t >> 6, l = t & 63;
    int l15 = l & 15, lhi = l >> 4;
    int wr = w >> 1, wc = w & 1;
    int m0 = (logical / NT) * 128;
    int n0 = (logical % NT) * 64;

    int trow = t >> 2, tcol = (t & 3) * 8;
    f32x4 acc[4][2] = {};

    for (int k0 = 0; k0 < CH; k0 += 32) {
        uint4 a0v = make_uint4(0, 0, 0, 0), a1v = make_uint4(0, 0, 0, 0);
        int ar0 = m0 + trow, ar1 = m0 + trow + 64;
        if (ar0 < MROWS) a0v = *(const uint4*)(A + (size_t)ar0 * CH + k0 + tcol);
        if (ar1 < MROWS) a1v = *(const uint4*)(A + (size_t)ar1 * CH + k0 + tcol);
        uint4 bv = *(const uint4*)(B + (size_t)(n0 + trow) * CH + k0 + tcol);
        if (k0) __syncthreads();
        *(uint4*)&As[trow][tcol] = a0v;
        *(uint4*)&As[trow + 64][tcol] = a1v;
        *(uint4*)&Bs[trow][tcol] = bv;
        __syncthreads();
        s16x8 af[4], bf[2];
        #pragma unroll
        for (int i = 0; i < 4; ++i)
            af[i] = *(const s16x8*)&As[wr * 64 + 16 * i + l15][lhi * 8];
        #pragma unroll
        for (int j = 0; j < 2; ++j)
            bf[j] = *(const s16x8*)&Bs[wc * 32 + 16 * j + l15][lhi * 8];
        #pragma unroll
        for (int i = 0; i < 4; ++i)
            #pragma unroll
            for (int j = 0; j < 2; ++j)
                acc[i][j] = MFMA16(af[i], bf[j], acc[i][j]);
    }

    #pragma unroll
    for (int i = 0; i < 4; ++i)
        #pragma unroll
        for (int j = 0; j < 2; ++j)
            #pragma unroll
            for (int r = 0; r < 4; ++r) {
                int mm = m0 + wr * 64 + 16 * i + lhi * 4 + r;
                if (mm >= MROWS) continue;
                int n = n0 + wc * 32 + 16 * j + l15;
                ushort_t val = f2bf(acc[i][j][r]);
                int b_ = mm / SEQ, tok = mm % SEQ;
                if (n < CH) {
                    int h = n >> 6, d = n & 63;
                    kbuf[((size_t)(b_ * HEADS + h) * NKPAD + tok) * 64 + d] = val;
                } else {
                    int c = n - CH, h = c >> 6, d = c & 63;
                    vtbuf[((size_t)(b_ * HEADS + h) * 64 + d) * NKPAD + tok] = val;
                }
            }
}

__global__ __launch_bounds__(256) void fused_gemms(
    const float* __restrict__ x, const float* __restrict__ w_qkv,
    float* __restrict__ q0, float* __restrict__ q1,
    const ushort_t* __restrict__ xb, const ushort_t* __restrict__ wkvT,
    ushort_t* __restrict__ kbuf, ushort_t* __restrict__ vtbuf)
{
    __shared__ __align__(16) char lds_raw[25600];
    int lin = blockIdx.x;                 // 0..1583 = 99 chunk-pairs x 16
    int xcd = lin & 7;
    int cls = (lin >> 3) & 1;
    int cc  = lin >> 4;                   // 0..98
    if (cls == 0) {
        kv_body(lds_raw, xcd * 99 + cc, xb, wkvT, kbuf, vtbuf);
    } else {
        int g = xcd * 99 + cc;            // 0..791 -> (tile, slab)
        fp32_body(lds_raw, g >> 1, g & 1, x, w_qkv, q0, q1);
    }
}

// ---------------- qtb = bf16(q0+q1) re-laid-out to (bh, tok, d) ----------------
__global__ __launch_bounds__(256) void qconv(const float* __restrict__ q0,
                                             const float* __restrict__ q1,
                                             ushort_t* __restrict__ qtb)
{
    int i = blockIdx.x * 256 + threadIdx.x;     // over MROWS * CH / 8
    if (i >= MROWS * CH / 8) return;
    int row = i / (CH / 8);
    int rem = i % (CH / 8);
    int b = row / SEQ, tok = row % SEQ;
    int h = rem >> 3, d8 = (rem & 7) * 8;
    const float* s0 = q0 + (size_t)row * CH + h * 64 + d8;
    const float* s1 = q1 + (size_t)row * CH + h * 64 + d8;
    ushort_t o[8];
    #pragma unroll
    for (int j = 0; j < 8; ++j) o[j] = f2bf(s0[j] + s1[j]);
    *(uint4*)(qtb + ((size_t)(b * HEADS + h) * NKPAD + tok) * 64 + d8) =
        *(const uint4*)o;
}

// ---------- projection: LDS-staged bf16 MFMA GEMM + bias (f32 out) ----------
__global__ __launch_bounds__(256) void projgemm(
    const ushort_t* __restrict__ A, const ushort_t* __restrict__ B,
    const float* __restrict__ bias, float* __restrict__ outp)
{
    __shared__ __align__(16) ushort_t As[128][40];
    __shared__ __align__(16) ushort_t Bs[64][40];
    const int NT = 12;
    int t = threadIdx.x, w = t >> 6, l = t & 63;
    int l15 = l & 15, lhi = l >> 4;
    int wr = w >> 1, wc = w & 1;
    int lin = blockIdx.x;
    int xcd = lin & 7, idx = lin >> 3;
    int logical = (xcd < 4 ? xcd * 50 : 200 + (xcd - 4) * 49) + idx;
    int m0 = (logical / NT) * 128;
    int n0 = (logical % NT) * 64;

    int trow = t >> 2, tcol = (t & 3) * 8;
    f32x4 acc[4][2] = {};

    for (int k0 = 0; k0 < CH; k0 += 32) {
        uint4 a0v = make_uint4(0, 0, 0, 0), a1v = make_uint4(0, 0, 0, 0);
        int ar0 = m0 + trow, ar1 = m0 + trow + 64;
        if (ar0 < MROWS) a0v = *(const uint4*)(A + (size_t)ar0 * CH + k0 + tcol);
        if (ar1 < MROWS) a1v = *(const uint4*)(A + (size_t)ar1 * CH + k0 + tcol);
        uint4 bv = *(const uint4*)(B + (size_t)(n0 + trow) * CH + k0 + tcol);
        if (k0) __syncthreads();
        *(uint4*)&As[trow][tcol] = a0v;
        *(uint4*)&As[trow + 64][tcol] = a1v;
        *(uint4*)&Bs[trow][tcol] = bv;
        __syncthreads();
        s16x8 af[4], bf[2];
        #pragma unroll
        for (int i = 0; i < 4; ++i)
            af[i] = *(const s16x8*)&As[wr * 64 + 16 * i + l15][lhi * 8];
        #pragma unroll
        for (int j = 0; j < 2; ++j)
            bf[j] = *(const s16x8*)&Bs[wc * 32 + 16 * j + l15][lhi * 8];
        #pragma unroll
        for (int i = 0; i < 4; ++i)
            #pragma unroll
            for (int j = 0; j < 2; ++j)
                acc[i][j] = MFMA16(af[i], bf[j], acc[i][j]);
    }

    #pragma unroll
    for (int i = 0; i < 4; ++i)
        #pragma unroll
        for (int j = 0; j < 2; ++j)
            #pragma unroll
            for (int r = 0; r < 4; ++r) {
                int m = m0 + wr * 64 + 16 * i + lhi * 4 + r;
                if (m >= MROWS) continue;
                int n = n0 + wc * 32 + 16 * j + l15;
                outp[(size_t)m * CH + n] = acc[i][j][r] + bias[n];
            }
}

// ---------------- q_sim (q = q0+q1, fp32) ----------------
__global__ __launch_bounds__(64) void qsim_kernel(
    const float* __restrict__ q0, const float* __restrict__ q1,
    const float* __restrict__ g, float* __restrict__ qsim)
{
    int idx = blockIdx.x;
    int b = idx >> 10, j = idx & 1023, n = j + 1;
    int lane = threadIdx.x;
    const float* r0 = q0 + (size_t)(b * SEQ + n) * CH;
    const float* r1 = q1 + (size_t)(b * SEQ + n) * CH;
    float acc = 0.f;
    for (int h = 0; h < HEADS; ++h) {
        float qv = r0[h * 64 + lane] + r1[h * 64 + lane];
        float gv = g[h * 64 + lane];
        float sqg = qv * gv, sqq = qv * qv, sgg = gv * gv;
        #pragma unroll
        for (int off = 32; off; off >>= 1) {
            sqg += __shfl_xor(sqg, off);
            sqq += __shfl_xor(sqq, off);
            sgg += __shfl_xor(sgg, off);
        }
        acc += sqg / sqrtf(sqq * sgg);
    }
    if (lane == 0) qsim[idx] = acc * (1.0f / HEADS);
}

// ---------------- min/max normalize + active bitmasks + N0 counts ----------------
__global__ __launch_bounds__(1024) void mask_kernel(
    const float* __restrict__ qsim, unsigned char* __restrict__ posm,
    unsigned char* __restrict__ vgrp,
    unsigned long long* __restrict__ actbits, float* __restrict__ n0arr)
{
    __shared__ float wmin[16], wmax[16];
    __shared__ unsigned int sbm[4 * 2 * 34];
    __shared__ int scnt[8];
    int t = threadIdx.x;
    if (t < 4 * 2 * 34) sbm[t] = 0u;
    if (t < 8) scnt[t] = 0;
    float v[4];
    float lmin = 1e30f, lmax = -1e30f;
    #pragma unroll
    for (int b = 0; b < 4; ++b) {
        v[b] = qsim[b * 1024 + t];
        lmin = fminf(lmin, v[b]); lmax = fmaxf(lmax, v[b]);
    }
    #pragma unroll
    for (int off = 32; off; off >>= 1) {
        lmin = fminf(lmin, __shfl_xor(lmin, off));
        lmax = fmaxf(lmax, __shfl_xor(lmax, off));
    }
    if ((t & 63) == 0) { wmin[t >> 6] = lmin; wmax[t >> 6] = lmax; }
    __syncthreads();
    if (t == 0) {
        float gmin = wmin[0], gmax = wmax[0];
        for (int i = 1; i < 16; ++i) { gmin = fminf(gmin, wmin[i]); gmax = fmaxf(gmax, wmax[i]); }
        wmin[0] = gmin; wmax[0] = gmax;
    }
    __syncthreads();
    float gmin = wmin[0], den = wmax[0] - gmin;
    int pb[4], anyp = 0, anyn = 0;
    #pragma unroll
    for (int b = 0; b < 4; ++b) {
        float s = (v[b] - gmin) / den;
        pb[b] = s > 0.9f ? 1 : 0;
        anyp |= pb[b]; anyn |= (1 - pb[b]);
    }
    int k = t + 1;
    int wd = k >> 5;
    unsigned bit = 1u << (k & 31);
    #pragma unroll
    for (int b = 0; b < 4; ++b) {
        if (pb[b]) atomicOr(&sbm[(b * 2 + 0) * 34 + wd], bit);
        else       atomicOr(&sbm[(b * 2 + 1) * 34 + wd], bit);
        unsigned long long bp = __ballot(anyp && !pb[b]);
        unsigned long long bn = __ballot(anyn && pb[b]);
        if ((t & 63) == 0) {
            atomicAdd(&scnt[b * 2 + 0], (int)__popcll(bp));
            atomicAdd(&scnt[b * 2 + 1], (int)__popcll(bn));
        }
        posm[b * 1024 + t] = (unsigned char)pb[b];
    }
    vgrp[2 + t] = (unsigned char)anyn;
    if (t < 2) vgrp[t] = (unsigned char)t;
    if (t < 62) vgrp[1026 + t] = 0;
    __syncthreads();
    if (t < 4 * 2 * 34) {
        unsigned vv = sbm[t];
        if ((t % 34) == 0) vv |= 1u;       // CLS key active in every (b,grp)
        ((unsigned int*)actbits)[t] = vv;
    }
    if (t < 8) n0arr[t] = (float)scnt[t];
}

// ---------------- MFMA grouped flash attention: 32 queries/block, KV split 4 waves ----
__global__ __launch_bounds__(256) void attn_mfma(
    const ushort_t* __restrict__ qtb, const ushort_t* __restrict__ kb,
    const ushort_t* __restrict__ vtb,
    const unsigned long long* __restrict__ actbits,
    const float* __restrict__ n0arr,
    const unsigned char* __restrict__ vgrp,
    const unsigned char* __restrict__ posm,
    ushort_t* __restrict__ xob, float* __restrict__ clsf)
{
    __shared__ __align__(16) float comb[4][64][18];   // 18432 B; front 16 KB = P staging

    int t = threadIdx.x, w = t >> 6, l = t & 63;
    int l15 = l & 15, lhi = l >> 4;

    // XCD-aware bijective remap: 1632 = 8 XCDs x (6 bh x 34 qb)
    int lin = blockIdx.y * NQB + blockIdx.x;
    int xcd = lin & 7, slot = lin >> 3;
    int bh = xcd * 6 + slot / NQB;
    int qb = slot % NQB;
    int b = bh / HEADS, h = bh % HEADS;

    int qv0 = qb * 32 + l15;             // this lane's two query columns
    int qv1 = qv0 + 16;
    int g0 = vgrp[qv0], g1 = vgrp[qv1];
    float n00 = n0arr[b * 2 + g0], n01 = n0arr[b * 2 + g1];
    float mq0 = 1.f, mq1 = 1.f;
    if (qv0 >= 2) {
        int j = qv0 - 2; if (j > 1023) j = 1023;
        int p = posm[b * 1024 + j];
        mq0 = (float)(g0 ? 1 - p : p);
    }
    {
        int j = qv1 - 2; if (j > 1023) j = 1023;
        int p = posm[b * 1024 + j];
        mq1 = (float)(g1 ? 1 - p : p);
    }
    float scl0 = SCALE2 * mq0, scl1 = SCALE2 * mq1;
    const unsigned long long* abp = actbits + (size_t)b * 2 * NTILE;
    const unsigned long long* abn = abp + NTILE;

    int tok0 = (qv0 < 2) ? 0 : qv0 - 1;
    int tok1 = qv1 - 1;                   // qv1 >= 16 always
    const ushort_t* qbb = qtb + (size_t)bh * NKPAD * 64 + lhi * 8;
    s16x8 bqA0 = *(const s16x8*)(qbb + (size_t)tok0 * 64);
    s16x8 bqA1 = *(const s16x8*)(qbb + (size_t)tok0 * 64 + 32);
    s16x8 bqB0 = *(const s16x8*)(qbb + (size_t)tok1 * 64);
    s16x8 bqB1 = *(const s16x8*)(qbb + (size_t)tok1 * 64 + 32);

    f32x4 out0[4] = {{0,0,0,0},{0,0,0,0},{0,0,0,0},{0,0,0,0}};
    f32x4 out1[4] = {{0,0,0,0},{0,0,0,0},{0,0,0,0},{0,0,0,0}};
    float mrow0 = -INFINITY, lrow0 = 0.f;
    float mrow1 = -INFINITY, lrow1 = 0.f;

    // induction pointers: K tile stride = 4*64*64 elem, V tile stride = 4*64 elem
    const ushort_t* kp = kb + (size_t)bh * NKPAD * 64 + (size_t)w * 4096 + l15 * 64 + lhi * 8;
    const ushort_t* vp = vtb + (size_t)bh * 64 * NKPAD + (size_t)l15 * NKPAD + w * 64 + lhi * 8;
    ushort_t* pw = (ushort_t*)&comb[0][0][0] + w * 2048;   // 2 groups x 1024
    int swz = (l15 & 7) << 3;

    for (int tile = w; tile < NTILE; tile += 4) {
        // ---- issue ALL 16 fragment loads up front (16-deep MLP) ----
        s16x8 kf[8], vf[8];
        #pragma unroll
        for (int tt = 0; tt < 4; ++tt) {
            kf[2 * tt]     = *(const s16x8*)(kp + 1024 * tt);
            kf[2 * tt + 1] = *(const s16x8*)(kp + 1024 * tt + 32);
        }
        #pragma unroll
        for (int dt = 0; dt < 4; ++dt) {
            const ushort_t* vpd = vp + (size_t)(16 * NKPAD) * dt;
            vf[2 * dt]     = *(const s16x8*)vpd;
            vf[2 * dt + 1] = *(const s16x8*)(vpd + 32);
        }
        // ---- QK for both query groups (waits on K only) ----
        f32x4 s0[4], s1[4];
        #pragma unroll
        for (int tt = 0; tt < 4; ++tt) {
            f32x4 a0 = {0, 0, 0, 0}, a1 = {0, 0, 0, 0};
            a0 = MFMA16(kf[2 * tt], bqA0, a0);
            a0 = MFMA16(kf[2 * tt + 1], bqA1, a0);
            a1 = MFMA16(kf[2 * tt], bqB0, a1);
            a1 = MFMA16(kf[2 * tt + 1], bqB1, a1);
            s0[tt] = a0; s1[tt] = a1;
        }
        unsigned long long amp_ = abp[tile], amn_ = abn[tile];
        // ---- group 0 softmax (V loads still in flight) ----
        {
            unsigned long long am = g0 ? amn_ : amp_;
            #pragma unroll
            for (int tt = 0; tt < 4; ++tt) {
                unsigned nib = (unsigned)(am >> (16 * tt + 4 * lhi)) & 0xFu;
                #pragma unroll
                for (int r = 0; r < 4; ++r)
                    s0[tt][r] = ((nib >> r) & 1u) ? s0[tt][r] * scl0 : -INFINITY;
            }
            float ma = max3f(s0[0][0], s0[0][1], s0[0][2]);
            float mb = max3f(s0[0][3], s0[1][0], s0[1][1]);
            float mc = max3f(s0[1][2], s0[1][3], s0[2][0]);
            float md = max3f(s0[2][1], s0[2][2], s0[2][3]);
            float me = max3f(s0[3][0], s0[3][1], s0[3][2]);
            float smax = fmaxf(max3f(ma, mb, mc), max3f(md, me, s0[3][3]));
            smax = fmaxf(smax, __shfl_xor(smax, 16));
            smax = fmaxf(smax, __shfl_xor(smax, 32));
            float mnew = fmaxf(mrow0, smax);
            float msafe = (mnew == -INFINITY) ? 0.f : mnew;
            float alpha = fast_exp2(mrow0 - msafe);
            mrow0 = mnew;
            #pragma unroll
            for (int tt = 0; tt < 4; ++tt)
                #pragma unroll
                for (int r = 0; r < 4; ++r)
                    s0[tt][r] = fast_exp2(s0[tt][r] - msafe);
            float l0 = (s0[0][0] + s0[0][1]) + (s0[0][2] + s0[0][3]);
            float l1 = (s0[1][0] + s0[1][1]) + (s0[1][2] + s0[1][3]);
            float l2 = (s0[2][0] + s0[2][1]) + (s0[2][2] + s0[2][3]);
            float l3 = (s0[3][0] + s0[3][1]) + (s0[3][2] + s0[3][3]);
            float ls = (l0 + l1) + (l2 + l3);
            ls += __shfl_xor(ls, 16);
            ls += __shfl_xor(ls, 32);
            lrow0 = lrow0 * alpha + ls;
            #pragma unroll
            for (int dt = 0; dt < 4; ++dt) out0[dt] *= alpha;
            #pragma unroll
            for (int tt = 0; tt < 4; ++tt) {
                unsigned lo = cvt_pk_bf16(s0[tt][0], s0[tt][1]);
                unsigned hi = cvt_pk_bf16(s0[tt][2], s0[tt][3]);
                int kk = 16 * tt + 4 * lhi;
                *(uint2*)&pw[(l15 * 64 + kk) ^ swz] = make_uint2(lo, hi);
            }
        }
        // ---- group 1 softmax ----
        {
            unsigned long long am = g1 ? amn_ : amp_;
            #pragma unroll
            for (int tt = 0; tt < 4; ++tt) {
                unsigned nib = (unsigned)(am >> (16 * tt + 4 * lhi)) & 0xFu;
                #pragma unroll
                for (int r = 0; r < 4; ++r)
                    s1[tt][r] = ((nib >> r) & 1u) ? s1[tt][r] * scl1 : -INFINITY;
            }
            float ma = max3f(s1[0][0], s1[0][1], s1[0][2]);
            float mb = max3f(s1[0][3], s1[1][0], s1[1][1]);
            float mc = max3f(s1[1][2], s1[1][3], s1[2][0]);
            float md = max3f(s1[2][1], s1[2][2], s1[2][3]);
            float me = max3f(s1[3][0], s1[3][1], s1[3][2]);
            float smax = fmaxf(max3f(ma, mb, mc), max3f(md, me, s1[3][3]));
            smax = fmaxf(smax, __shfl_xor(smax, 16));
            smax = fmaxf(smax, __shfl_xor(smax, 32));
            float mnew = fmaxf(mrow1, smax);
            float msafe = (mnew == -INFINITY) ? 0.f : mnew;
            float alpha = fast_exp2(mrow1 - msafe);
            mrow1 = mnew;
            #pragma unroll
            for (int tt = 0; tt < 4; ++tt)
                #pragma unroll
                for (int r = 0; r < 4; ++r)
                    s1[tt][r] = fast_exp2(s1[tt][r] - msafe);
            float l0 = (s1[0][0] + s1[0][1]) + (s1[0][2] + s1[0][3]);
            float l1 = (s1[1][0] + s1[1][1]) + (s1[1][2] + s1[1][3]);
            float l2 = (s1[2][0] + s1[2][1]) + (s1[2][2] + s1[2][3]);
            float l3 = (s1[3][0] + s1[3][1]) + (s1[3][2] + s1[3][3]);
            float ls = (l0 + l1) + (l2 + l3);
            ls += __shfl_xor(ls, 16);
            ls += __shfl_xor(ls, 32);
            lrow1 = lrow1 * alpha + ls;
            #pragma unroll
            for (int dt = 0; dt < 4; ++dt) out1[dt] *= alpha;
            #pragma unroll
            for (int tt = 0; tt < 4; ++tt) {
                unsigned lo = cvt_pk_bf16(s1[tt][0], s1[tt][1]);
                unsigned hi = cvt_pk_bf16(s1[tt][2], s1[tt][3]);
                int kk = 16 * tt + 4 * lhi;
                *(uint2*)&pw[1024 + ((l15 * 64 + kk) ^ swz)] = make_uint2(lo, hi);
            }
        }
        // ---- PV for both groups (vf resident by now) ----
        s16x8 pa0 = *(const s16x8*)&pw[(l15 * 64 + lhi * 8) ^ swz];
        s16x8 pa1 = *(const s16x8*)&pw[(l15 * 64 + 32 + lhi * 8) ^ swz];
        s16x8 pb0 = *(const s16x8*)&pw[1024 + ((l15 * 64 + lhi * 8) ^ swz)];
        s16x8 pb1 = *(const s16x8*)&pw[1024 + ((l15 * 64 + 32 + lhi * 8) ^ swz)];
        #pragma unroll
        for (int dt = 0; dt < 4; ++dt) {
            out0[dt] = MFMA16(vf[2 * dt], pa0, out0[dt]);
            out0[dt] = MFMA16(vf[2 * dt + 1], pa1, out0[dt]);
            out1[dt] = MFMA16(vf[2 * dt], pb0, out1[dt]);
            out1[dt] = MFMA16(vf[2 * dt + 1], pb1, out1[dt]);
        }
        kp += 4 * 4096;
        vp += 4 * 64;
    }

    // ---- two-pass flash merge (reuse one 18.4 KB LDS buffer) ----
    #pragma unroll
    for (int pass = 0; pass < 2; ++pass) {
        __syncthreads();
        {
            const f32x4* o = pass ? out1 : out0;
            #pragma unroll
            for (int dt = 0; dt < 4; ++dt) *(f32x4*)&comb[w][l][4 * dt] = o[dt];
            comb[w][l][16] = pass ? mrow1 : mrow0;
            comb[w][l][17] = pass ? lrow1 : lrow0;
        }
        __syncthreads();
        if (w == 0) {
            int qv = pass ? qv1 : qv0;
            float n0 = pass ? n01 : n00;
            float M = fmaxf(fmaxf(comb[0][l][16], comb[1][l][16]),
                            fmaxf(comb[2][l][16], comb[3][l][16]));
            if (n0 > 0.f) M = fmaxf(M, 0.f);
            float L = n0 * fast_exp2(0.f - M);
            f32x4 o[4] = {{0,0,0,0},{0,0,0,0},{0,0,0,0},{0,0,0,0}};
            #pragma unroll
            for (int w2 = 0; w2 < 4; ++w2) {
                float a = fast_exp2(comb[w2][l][16] - M);
                L += comb[w2][l][17] * a;
                #pragma unroll
                for (int dt = 0; dt < 4; ++dt)
                    o[dt] += *(const f32x4*)&comb[w2][l][4 * dt] * a;
            }
            float invl = 1.0f / L;
            if (qv <= 1025) {
                if (qv >= 2) {
                    int n = qv - 1;
                    ushort_t* dst = xob + (size_t)(b * SEQ + n) * CH + h * 64 + 4 * lhi;
                    #pragma unroll
                    for (int dt = 0; dt < 4; ++dt) {
                        unsigned lo = cvt_pk_bf16(o[dt][0] * invl, o[dt][1] * invl);
                        unsigned hi = cvt_pk_bf16(o[dt][2] * invl, o[dt][3] * invl);
                        *(uint2*)(dst + 16 * dt) = make_uint2(lo, hi);
                    }
                } else {
                    float* dst = clsf + (size_t)(qv * BATCH + b) * CH + h * 64 + 4 * lhi;
                    #pragma unroll
                    for (int dt = 0; dt < 4; ++dt)
                        #pragma unroll
                        for (int r = 0; r < 4; ++r)
                            dst[16 * dt + r] = o[dt][r] * invl;
                }
            }
        }
    }
}

// ---------------- CLS combine into xob row 0 ----------------
__global__ __launch_bounds__(768) void cls_combine(
    const float* __restrict__ clsf, ushort_t* __restrict__ xob)
{
    int b = blockIdx.x, c = threadIdx.x;
    float v = 0.5f * (clsf[(size_t)b * CH + c] + clsf[(size_t)(BATCH + b) * CH + c]);
    xob[(size_t)b * SEQ * CH + c] = f2bf(v);
}

extern "C" void kernel_launch(void* const* d_in, const int* in_sizes, int n_in,
                              void* d_out, int out_size, void* d_ws, size_t ws_size,
                              hipStream_t stream) {
    const float* x      = (const float*)d_in[0];
    const float* g_info = (const float*)d_in[1];
    const float* w_qkv  = (const float*)d_in[2];
    const float* w_proj = (const float*)d_in[3];
    const float* b_proj = (const float*)d_in[4];
    float* out = (float*)d_out;
    char* ws = (char*)d_ws;

    size_t off = 0;
    auto alloc = [&](size_t bytes) { size_t o = off; off += (bytes + 255) & ~(size_t)255; return o; };
    float*    qf    = (float*)(ws + alloc((size_t)MROWS * CH * 4));
    ushort_t* xb    = (ushort_t*)(ws + alloc((size_t)MROWS * CH * 2));
    ushort_t* wkvT  = (ushort_t*)(ws + alloc((size_t)2 * CH * CH * 2));
    ushort_t* wpT   = (ushort_t*)(ws + alloc((size_t)CH * CH * 2));
    ushort_t* qtb   = (ushort_t*)(ws + alloc((size_t)NBH * NKPAD * 64 * 2));
    ushort_t* kbuf  = (ushort_t*)(ws + alloc((size_t)NBH * NKPAD * 64 * 2));
    ushort_t* vtbuf = (ushort_t*)(ws + alloc((size_t)NBH * NKPAD * 64 * 2));
    ushort_t* xob   = (ushort_t*)(ws + alloc((size_t)MROWS * CH * 2));
    float*    clsf  = (float*)(ws + alloc((size_t)2 * BATCH * CH * 4));
    float*    qsim  = (float*)(ws + alloc((size_t)BATCH * 1024 * 4));
    unsigned char* posm = (unsigned char*)(ws + alloc((size_t)BATCH * 1024));
    unsigned long long* actbits = (unsigned long long*)(ws + alloc((size_t)BATCH * 2 * NTILE * 8));
    float* n0arr = (float*)(ws + alloc((size_t)8 * 4));
    unsigned char* vgrp = (unsigned char*)(ws + alloc((size_t)NKPAD));

    // slab-1 partial reuses d_out (projgemm overwrites it at the end)
    float* qpart = out;

    // fused prep: convx + convT(wkv) + convT(wp) + zeropad
    prep<<<5559, 256, 0, stream>>>(x, xb, w_qkv, wkvT, w_proj, wpT, kbuf, vtbuf, qtb);

    // fused fp32 q GEMM (8x4 microtile, split-K=2) + bf16 K/V GEMM
    fused_gemms<<<1584, 256, 0, stream>>>(x, w_qkv, qf, qpart, xb, wkvT, kbuf, vtbuf);

    // masks + q cast (q = qf + qpart)
    qsim_kernel<<<BATCH * 1024, 64, 0, stream>>>(qf, qpart, g_info, qsim);
    mask_kernel<<<1, 1024, 0, stream>>>(qsim, posm, vgrp, actbits, n0arr);
    qconv<<<(MROWS * CH / 8 + 255) / 256, 256, 0, stream>>>(qf, qpart, qtb);

    // attention (32 queries/block, 4-way KV split, batched loads)
    attn_mfma<<<dim3(NQB, NBH), 256, 0, stream>>>(
        qtb, kbuf, vtbuf, actbits, n0arr, vgrp, posm, xob, clsf);
    cls_combine<<<BATCH, CH, 0, stream>>>(clsf, xob);

    // projection (LDS-staged, XCD-bijective) — overwrites d_out
    projgemm<<<396, 256, 0, stream>>>(xob, wpT, b_proj, out);

    // tail output: g_info[1:]
    hipMemcpyAsync(out + (size_t)MROWS * CH, g_info + 2 * CH, (size_t)2 * CH * sizeof(float),
                   hipMemcpyDeviceToDevice, stream);
}

// Round 23
// 209.303 us; speedup vs baseline: 1.1335x; 1.1335x over previous
//
#include <hip/hip_runtime.h>
#include <math.h>

typedef unsigned short ushort_t;
typedef short s16x8 __attribute__((ext_vector_type(8)));
typedef float f32x4 __attribute__((ext_vector_type(4)));

#define MFMA16(a, b, c) __builtin_amdgcn_mfma_f32_16x16x32_bf16(a, b, c, 0, 0, 0)

#define BATCH 4
#define SEQ   1025
#define CH    768
#define HEADS 12
#define NBH   48
#define NKPAD 1088
#define NTILE 17
#define NQB   34          // 1088 / 32 query blocks
#define MROWS 4100
#define SCALE2 0.18033688011112042f   // 0.125 * log2(e)

__device__ __forceinline__ ushort_t f2bf(float f) {
    unsigned u = __builtin_bit_cast(unsigned, f);
    u += 0x7FFFu + ((u >> 16) & 1u);
    return (ushort_t)(u >> 16);
}
__device__ __forceinline__ unsigned cvt_pk_bf16(float lo, float hi) {
    unsigned r;
    asm("v_cvt_pk_bf16_f32 %0, %1, %2" : "=v"(r) : "v"(lo), "v"(hi));
    return r;
}
__device__ __forceinline__ float max3f(float a, float b, float c) {
    float r;
    asm("v_max3_f32 %0, %1, %2, %3" : "=v"(r) : "v"(a), "v"(b), "v"(c));
    return r;
}
__device__ __forceinline__ float fast_exp2(float x) {
    float r; asm("v_exp_f32 %0, %1" : "=v"(r) : "v"(x)); return r;
}

// ================== fused prep: convx + convT(wkv) + convT(wp) + zeropad ==================
__global__ __launch_bounds__(256) void prep(
    const float* __restrict__ x, ushort_t* __restrict__ xb,
    const float* __restrict__ w_qkv, ushort_t* __restrict__ wkvT,
    const float* __restrict__ w_proj, ushort_t* __restrict__ wpT,
    ushort_t* __restrict__ kbuf, ushort_t* __restrict__ vtbuf, ushort_t* __restrict__ qtb)
{
    __shared__ float tile[32][33];
    int b = blockIdx.x, t = threadIdx.x;
    if (b < 3075) {                       // convx: x f32 -> bf16 (787200 float4s)
        int i = b * 256 + t;
        float4 v = ((const float4*)x)[i];
        ushort_t o[4] = {f2bf(v.x), f2bf(v.y), f2bf(v.z), f2bf(v.w)};
        *(uint2*)(xb + (size_t)i * 4) = *(const uint2*)o;
        return;
    }
    const float* src; ushort_t* dst; int ld, c0, k0, n0;
    if (b < 3075 + 1152) {                // convT wkv: dst[n][k]=bf16(w_qkv[k][CH+n])
        int j = b - 3075;
        src = w_qkv; dst = wkvT; ld = 3 * CH; c0 = CH;
        k0 = (j % 24) * 32; n0 = (j / 24) * 32;
    } else if (b < 3075 + 1152 + 576) {   // convT wp
        int j = b - 3075 - 1152;
        src = w_proj; dst = wpT; ld = CH; c0 = 0;
        k0 = (j % 24) * 32; n0 = (j / 24) * 32;
    } else {                              // zeropad (756 blocks x 256 = 193536)
        int i = (b - 4803) * 256 + t;
        {   // kbuf + qtb rows 1025..1087
            int bh = i / (63 * 64), rem = i % (63 * 64);
            kbuf[((size_t)bh * NKPAD + 1025 + rem / 64) * 64 + (rem & 63)] = 0;
            qtb [((size_t)bh * NKPAD + 1025 + rem / 64) * 64 + (rem & 63)] = 0;
        }
        {   // vtb cols 1025..1087
            int bh = i / (64 * 63), rem = i % (64 * 63);
            vtbuf[((size_t)bh * 64 + rem / 63) * NKPAD + 1025 + rem % 63] = 0;
        }
        return;
    }
    int tx = t & 31, ty = t >> 5;
    #pragma unroll
    for (int i = 0; i < 32; i += 8)
        tile[ty + i][tx] = src[(size_t)(k0 + ty + i) * ld + c0 + n0 + tx];
    __syncthreads();
    #pragma unroll
    for (int i = 0; i < 32; i += 8)
        dst[(size_t)(n0 + ty + i) * CH + k0 + tx] = f2bf(tile[tx][ty + i]);
}

// ================== fused GEMMs (r21 config): fp32 q (split-K=2) + bf16 K/V ==================
// 2376 blocks, lin%3==0 -> KV-MFMA, else fp32. Physical-XCD-derived remaps
// (gcd(3,8)=1 keeps both classes bijective). Measured 104 us (r20/r21);
// r17/r22 proved the 4x4/64x64 high-occupancy shape is the fp32 optimum.

__device__ __forceinline__ void fp32_body(char* lds, int logical, int slab,
    const float* __restrict__ A, const float* __restrict__ Bm,
    float* __restrict__ C0, float* __restrict__ C1)
{
    float (*As)[68] = (float(*)[68])lds;
    float (*Bs)[64] = (float(*)[64])(lds + 32 * 68 * 4);
    const int M = MROWS, K = CH, ldb = 3 * CH, Nn = CH;
    int t = threadIdx.x;
    int m0 = (logical / 12) * 64, n0 = (logical % 12) * 64;
    int kbase = slab * 384;
    float* __restrict__ Cm = slab ? C1 : C0;

    int ty = t >> 4, tx = t & 15;
    int laRow = t >> 2, laK = (t & 3) * 4;
    int lbK = t >> 4, lbN = (t & 15) * 4;
    float acc[4][4] = {};
    for (int k0 = kbase; k0 < kbase + 384; k0 += 32) {
        int arow = m0 + laRow;
        #pragma unroll
        for (int half = 0; half < 2; ++half) {
            float4 av = make_float4(0.f, 0.f, 0.f, 0.f);
            if (arow < M) av = *(const float4*)(A + (size_t)arow * K + k0 + laK + 16 * half);
            As[laK + 16 * half + 0][laRow] = av.x;
            As[laK + 16 * half + 1][laRow] = av.y;
            As[laK + 16 * half + 2][laRow] = av.z;
            As[laK + 16 * half + 3][laRow] = av.w;
            *(float4*)&Bs[lbK + 16 * half][lbN] =
                *(const float4*)(Bm + (size_t)(k0 + lbK + 16 * half) * ldb + n0 + lbN);
        }
        __syncthreads();
        #pragma unroll
        for (int kk = 0; kk < 32; ++kk) {
            float4 a4 = *(const float4*)&As[kk][ty * 4];
            float4 b4 = *(const float4*)&Bs[kk][tx * 4];
            float a[4] = {a4.x, a4.y, a4.z, a4.w};
            float b[4] = {b4.x, b4.y, b4.z, b4.w};
            #pragma unroll
            for (int i = 0; i < 4; ++i)
                #pragma unroll
                for (int j = 0; j < 4; ++j) acc[i][j] += a[i] * b[j];
        }
        __syncthreads();
    }
    #pragma unroll
    for (int i = 0; i < 4; ++i) {
        int row = m0 + ty * 4 + i;
        if (row >= M) continue;
        #pragma unroll
        for (int j = 0; j < 4; ++j)
            Cm[(size_t)row * Nn + n0 + tx * 4 + j] = acc[i][j];
    }
}

__device__ __forceinline__ void kv_body(char* lds, int logical,
    const ushort_t* __restrict__ A, const ushort_t* __restrict__ B,
    ushort_t* __restrict__ kbuf, ushort_t* __restrict__ vtbuf)
{
    ushort_t (*As)[40] = (ushort_t(*)[40])lds;
    ushort_t (*Bs)[40] = (ushort_t(*)[40])(lds + 128 * 40 * 2);
    const int NT = 24;
    int t = threadIdx.x, w = t >> 6, l = t & 63;
    int l15 = l & 15, lhi = l >> 4;
    int wr = w >> 1, wc = w & 1;
    int m0 = (logical / NT) * 128;
    int n0 = (logical % NT) * 64;

    int trow = t >> 2, tcol = (t & 3) * 8;
    f32x4 acc[4][2] = {};

    for (int k0 = 0; k0 < CH; k0 += 32) {
        uint4 a0v = make_uint4(0, 0, 0, 0), a1v = make_uint4(0, 0, 0, 0);
        int ar0 = m0 + trow, ar1 = m0 + trow + 64;
        if (ar0 < MROWS) a0v = *(const uint4*)(A + (size_t)ar0 * CH + k0 + tcol);
        if (ar1 < MROWS) a1v = *(const uint4*)(A + (size_t)ar1 * CH + k0 + tcol);
        uint4 bv = *(const uint4*)(B + (size_t)(n0 + trow) * CH + k0 + tcol);
        if (k0) __syncthreads();
        *(uint4*)&As[trow][tcol] = a0v;
        *(uint4*)&As[trow + 64][tcol] = a1v;
        *(uint4*)&Bs[trow][tcol] = bv;
        __syncthreads();
        s16x8 af[4], bf[2];
        #pragma unroll
        for (int i = 0; i < 4; ++i)
            af[i] = *(const s16x8*)&As[wr * 64 + 16 * i + l15][lhi * 8];
        #pragma unroll
        for (int j = 0; j < 2; ++j)
            bf[j] = *(const s16x8*)&Bs[wc * 32 + 16 * j + l15][lhi * 8];
        #pragma unroll
        for (int i = 0; i < 4; ++i)
            #pragma unroll
            for (int j = 0; j < 2; ++j)
                acc[i][j] = MFMA16(af[i], bf[j], acc[i][j]);
    }

    #pragma unroll
    for (int i = 0; i < 4; ++i)
        #pragma unroll
        for (int j = 0; j < 2; ++j)
            #pragma unroll
            for (int r = 0; r < 4; ++r) {
                int mm = m0 + wr * 64 + 16 * i + lhi * 4 + r;
                if (mm >= MROWS) continue;
                int n = n0 + wc * 32 + 16 * j + l15;
                ushort_t val = f2bf(acc[i][j][r]);
                int b_ = mm / SEQ, tok = mm % SEQ;
                if (n < CH) {
                    int h = n >> 6, d = n & 63;
                    kbuf[((size_t)(b_ * HEADS + h) * NKPAD + tok) * 64 + d] = val;
                } else {
                    int c = n - CH, h = c >> 6, d = c & 63;
                    vtbuf[((size_t)(b_ * HEADS + h) * 64 + d) * NKPAD + tok] = val;
                }
            }
}

__global__ __launch_bounds__(256) void fused_gemms(
    const float* __restrict__ x, const float* __restrict__ w_qkv,
    float* __restrict__ q0, float* __restrict__ q1,
    const ushort_t* __restrict__ xb, const ushort_t* __restrict__ wkvT,
    ushort_t* __restrict__ kbuf, ushort_t* __restrict__ vtbuf)
{
    __shared__ __align__(16) char lds_raw[16896];
    int lin = blockIdx.x;
    int q = lin / 3, r3 = lin - 3 * q;
    int xcd = lin & 7;
    if (r3 == 0) {
        kv_body(lds_raw, xcd * 99 + (q >> 3), xb, wkvT, kbuf, vtbuf);
    } else {
        int period = lin / 24;
        int s = lin - period * 24;
        const unsigned rank1 = (1u<<10)|(1u<<13)|(1u<<16)|(1u<<17)|(1u<<19)|(1u<<20)|(1u<<22)|(1u<<23);
        int rank = (rank1 >> s) & 1;
        int bx = xcd * 99 + period;
        if (bx >= 780) return;
        fp32_body(lds_raw, bx, rank, x, w_qkv, q0, q1);
    }
}

// ======= qmix: q = q0+q1 -> qtb (bf16) AND qsim (cosine-sim mean) in ONE pass =======
// One block per (b,tok) row, 768 threads = 12 waves (one per head). Wave h runs the
// SAME 64-lane butterfly as the old qsim kernel; thread 0 sums the 12 per-head
// terms in ascending h (identical fp32 order) -> qsim bits unchanged.
__global__ __launch_bounds__(768) void qmix(
    const float* __restrict__ q0, const float* __restrict__ q1,
    const float* __restrict__ g,
    ushort_t* __restrict__ qtb, float* __restrict__ qsim)
{
    __shared__ float hsum[12];
    int row = blockIdx.x;               // 0..4099 = b*SEQ + tok
    int t = threadIdx.x;                // 0..767
    int h = t >> 6, lane = t & 63;
    int b = row / SEQ, tok = row % SEQ;
    float qv = q0[(size_t)row * CH + t] + q1[(size_t)row * CH + t];
    qtb[((size_t)(b * HEADS + h) * NKPAD + tok) * 64 + lane] = f2bf(qv);
    float gv = g[t];
    float sqg = qv * gv, sqq = qv * qv, sgg = gv * gv;
    #pragma unroll
    for (int off = 32; off; off >>= 1) {
        sqg += __shfl_xor(sqg, off);
        sqq += __shfl_xor(sqq, off);
        sgg += __shfl_xor(sgg, off);
    }
    if (lane == 0) hsum[h] = sqg / sqrtf(sqq * sgg);
    __syncthreads();
    if (t == 0 && tok >= 1) {
        float acc = 0.f;
        #pragma unroll
        for (int i = 0; i < HEADS; ++i) acc += hsum[i];
        qsim[b * 1024 + (tok - 1)] = acc * (1.0f / HEADS);
    }
}

// ---------- projection: LDS-staged bf16 MFMA GEMM + bias (f32 out) ----------
__global__ __launch_bounds__(256) void projgemm(
    const ushort_t* __restrict__ A, const ushort_t* __restrict__ B,
    const float* __restrict__ bias, float* __restrict__ outp)
{
    __shared__ __align__(16) ushort_t As[128][40];
    __shared__ __align__(16) ushort_t Bs[64][40];
    const int NT = 12;
    int t = threadIdx.x, w = t >> 6, l = t & 63;
    int l15 = l & 15, lhi = l >> 4;
    int wr = w >> 1, wc = w & 1;
    int lin = blockIdx.x;
    int xcd = lin & 7, idx = lin >> 3;
    int logical = (xcd < 4 ? xcd * 50 : 200 + (xcd - 4) * 49) + idx;
    int m0 = (logical / NT) * 128;
    int n0 = (logical % NT) * 64;

    int trow = t >> 2, tcol = (t & 3) * 8;
    f32x4 acc[4][2] = {};

    for (int k0 = 0; k0 < CH; k0 += 32) {
        uint4 a0v = make_uint4(0, 0, 0, 0), a1v = make_uint4(0, 0, 0, 0);
        int ar0 = m0 + trow, ar1 = m0 + trow + 64;
        if (ar0 < MROWS) a0v = *(const uint4*)(A + (size_t)ar0 * CH + k0 + tcol);
        if (ar1 < MROWS) a1v = *(const uint4*)(A + (size_t)ar1 * CH + k0 + tcol);
        uint4 bv = *(const uint4*)(B + (size_t)(n0 + trow) * CH + k0 + tcol);
        if (k0) __syncthreads();
        *(uint4*)&As[trow][tcol] = a0v;
        *(uint4*)&As[trow + 64][tcol] = a1v;
        *(uint4*)&Bs[trow][tcol] = bv;
        __syncthreads();
        s16x8 af[4], bf[2];
        #pragma unroll
        for (int i = 0; i < 4; ++i)
            af[i] = *(const s16x8*)&As[wr * 64 + 16 * i + l15][lhi * 8];
        #pragma unroll
        for (int j = 0; j < 2; ++j)
            bf[j] = *(const s16x8*)&Bs[wc * 32 + 16 * j + l15][lhi * 8];
        #pragma unroll
        for (int i = 0; i < 4; ++i)
            #pragma unroll
            for (int j = 0; j < 2; ++j)
                acc[i][j] = MFMA16(af[i], bf[j], acc[i][j]);
    }

    #pragma unroll
    for (int i = 0; i < 4; ++i)
        #pragma unroll
        for (int j = 0; j < 2; ++j)
            #pragma unroll
            for (int r = 0; r < 4; ++r) {
                int m = m0 + wr * 64 + 16 * i + lhi * 4 + r;
                if (m >= MROWS) continue;
                int n = n0 + wc * 32 + 16 * j + l15;
                outp[(size_t)m * CH + n] = acc[i][j][r] + bias[n];
            }
}

// ---------------- min/max normalize + active bitmasks + N0 counts ----------------
__global__ __launch_bounds__(1024) void mask_kernel(
    const float* __restrict__ qsim, unsigned char* __restrict__ posm,
    unsigned char* __restrict__ vgrp,
    unsigned long long* __restrict__ actbits, float* __restrict__ n0arr)
{
    __shared__ float wmin[16], wmax[16];
    __shared__ unsigned int sbm[4 * 2 * 34];
    __shared__ int scnt[8];
    int t = threadIdx.x;
    if (t < 4 * 2 * 34) sbm[t] = 0u;
    if (t < 8) scnt[t] = 0;
    float v[4];
    float lmin = 1e30f, lmax = -1e30f;
    #pragma unroll
    for (int b = 0; b < 4; ++b) {
        v[b] = qsim[b * 1024 + t];
        lmin = fminf(lmin, v[b]); lmax = fmaxf(lmax, v[b]);
    }
    #pragma unroll
    for (int off = 32; off; off >>= 1) {
        lmin = fminf(lmin, __shfl_xor(lmin, off));
        lmax = fmaxf(lmax, __shfl_xor(lmax, off));
    }
    if ((t & 63) == 0) { wmin[t >> 6] = lmin; wmax[t >> 6] = lmax; }
    __syncthreads();
    if (t == 0) {
        float gmin = wmin[0], gmax = wmax[0];
        for (int i = 1; i < 16; ++i) { gmin = fminf(gmin, wmin[i]); gmax = fmaxf(gmax, wmax[i]); }
        wmin[0] = gmin; wmax[0] = gmax;
    }
    __syncthreads();
    float gmin = wmin[0], den = wmax[0] - gmin;
    int pb[4], anyp = 0, anyn = 0;
    #pragma unroll
    for (int b = 0; b < 4; ++b) {
        float s = (v[b] - gmin) / den;
        pb[b] = s > 0.9f ? 1 : 0;
        anyp |= pb[b]; anyn |= (1 - pb[b]);
    }
    int k = t + 1;
    int wd = k >> 5;
    unsigned bit = 1u << (k & 31);
    #pragma unroll
    for (int b = 0; b < 4; ++b) {
        if (pb[b]) atomicOr(&sbm[(b * 2 + 0) * 34 + wd], bit);
        else       atomicOr(&sbm[(b * 2 + 1) * 34 + wd], bit);
        unsigned long long bp = __ballot(anyp && !pb[b]);
        unsigned long long bn = __ballot(anyn && pb[b]);
        if ((t & 63) == 0) {
            atomicAdd(&scnt[b * 2 + 0], (int)__popcll(bp));
            atomicAdd(&scnt[b * 2 + 1], (int)__popcll(bn));
        }
        posm[b * 1024 + t] = (unsigned char)pb[b];
    }
    vgrp[2 + t] = (unsigned char)anyn;
    if (t < 2) vgrp[t] = (unsigned char)t;
    if (t < 62) vgrp[1026 + t] = 0;
    __syncthreads();
    if (t < 4 * 2 * 34) {
        unsigned vv = sbm[t];
        if ((t % 34) == 0) vv |= 1u;       // CLS key active in every (b,grp)
        ((unsigned int*)actbits)[t] = vv;
    }
    if (t < 8) n0arr[t] = (float)scnt[t];
}

// ---------------- qtb query-mask fold is applied in-attn as scalar (mq) ----------------
// ---------------- MFMA grouped flash attention: 32 queries/block, KV split 4 waves ----
__global__ __launch_bounds__(256) void attn_mfma(
    const ushort_t* __restrict__ qtb, const ushort_t* __restrict__ kb,
    const ushort_t* __restrict__ vtb,
    const unsigned long long* __restrict__ actbits,
    const float* __restrict__ n0arr,
    const unsigned char* __restrict__ vgrp,
    const unsigned char* __restrict__ posm,
    ushort_t* __restrict__ xob, float* __restrict__ clsf)
{
    __shared__ __align__(16) float comb[4][64][18];   // 18432 B; front 16 KB = P staging

    int t = threadIdx.x, w = t >> 6, l = t & 63;
    int l15 = l & 15, lhi = l >> 4;

    // XCD-aware bijective remap: 1632 = 8 XCDs x (6 bh x 34 qb)
    int lin = blockIdx.y * NQB + blockIdx.x;
    int xcd = lin & 7, slot = lin >> 3;
    int bh = xcd * 6 + slot / NQB;
    int qb = slot % NQB;
    int b = bh / HEADS, h = bh % HEADS;

    int qv0 = qb * 32 + l15;             // this lane's two query columns
    int qv1 = qv0 + 16;
    int g0 = vgrp[qv0], g1 = vgrp[qv1];
    float n00 = n0arr[b * 2 + g0], n01 = n0arr[b * 2 + g1];
    float mq0 = 1.f, mq1 = 1.f;
    if (qv0 >= 2) {
        int j = qv0 - 2; if (j > 1023) j = 1023;
        int p = posm[b * 1024 + j];
        mq0 = (float)(g0 ? 1 - p : p);
    }
    {
        int j = qv1 - 2; if (j > 1023) j = 1023;
        int p = posm[b * 1024 + j];
        mq1 = (float)(g1 ? 1 - p : p);
    }
    float scl0 = SCALE2 * mq0, scl1 = SCALE2 * mq1;
    const unsigned long long* abp = actbits + (size_t)b * 2 * NTILE;
    const unsigned long long* abn = abp + NTILE;

    int tok0 = (qv0 < 2) ? 0 : qv0 - 1;
    int tok1 = qv1 - 1;                   // qv1 >= 16 always
    const ushort_t* qbb = qtb + (size_t)bh * NKPAD * 64 + lhi * 8;
    s16x8 bqA0 = *(const s16x8*)(qbb + (size_t)tok0 * 64);
    s16x8 bqA1 = *(const s16x8*)(qbb + (size_t)tok0 * 64 + 32);
    s16x8 bqB0 = *(const s16x8*)(qbb + (size_t)tok1 * 64);
    s16x8 bqB1 = *(const s16x8*)(qbb + (size_t)tok1 * 64 + 32);

    f32x4 out0[4] = {{0,0,0,0},{0,0,0,0},{0,0,0,0},{0,0,0,0}};
    f32x4 out1[4] = {{0,0,0,0},{0,0,0,0},{0,0,0,0},{0,0,0,0}};
    float mrow0 = -INFINITY, lrow0 = 0.f;
    float mrow1 = -INFINITY, lrow1 = 0.f;

    // induction pointers: K tile stride = 4*64*64 elem, V tile stride = 4*64 elem
    const ushort_t* kp = kb + (size_t)bh * NKPAD * 64 + (size_t)w * 4096 + l15 * 64 + lhi * 8;
    const ushort_t* vp = vtb + (size_t)bh * 64 * NKPAD + (size_t)l15 * NKPAD + w * 64 + lhi * 8;
    ushort_t* pw = (ushort_t*)&comb[0][0][0] + w * 2048;   // 2 groups x 1024
    int swz = (l15 & 7) << 3;

    for (int tile = w; tile < NTILE; tile += 4) {
        // ---- issue ALL 16 fragment loads up front (16-deep MLP) ----
        s16x8 kf[8], vf[8];
        #pragma unroll
        for (int tt = 0; tt < 4; ++tt) {
            kf[2 * tt]     = *(const s16x8*)(kp + 1024 * tt);
            kf[2 * tt + 1] = *(const s16x8*)(kp + 1024 * tt + 32);
        }
        #pragma unroll
        for (int dt = 0; dt < 4; ++dt) {
            const ushort_t* vpd = vp + (size_t)(16 * NKPAD) * dt;
            vf[2 * dt]     = *(const s16x8*)vpd;
            vf[2 * dt + 1] = *(const s16x8*)(vpd + 32);
        }
        // ---- QK for both query groups (waits on K only) ----
        f32x4 s0[4], s1[4];
        #pragma unroll
        for (int tt = 0; tt < 4; ++tt) {
            f32x4 a0 = {0, 0, 0, 0}, a1 = {0, 0, 0, 0};
            a0 = MFMA16(kf[2 * tt], bqA0, a0);
            a0 = MFMA16(kf[2 * tt + 1], bqA1, a0);
            a1 = MFMA16(kf[2 * tt], bqB0, a1);
            a1 = MFMA16(kf[2 * tt + 1], bqB1, a1);
            s0[tt] = a0; s1[tt] = a1;
        }
        unsigned long long amp_ = abp[tile], amn_ = abn[tile];
        // ---- group 0 softmax (V loads still in flight) ----
        {
            unsigned long long am = g0 ? amn_ : amp_;
            #pragma unroll
            for (int tt = 0; tt < 4; ++tt) {
                unsigned nib = (unsigned)(am >> (16 * tt + 4 * lhi)) & 0xFu;
                #pragma unroll
                for (int r = 0; r < 4; ++r)
                    s0[tt][r] = ((nib >> r) & 1u) ? s0[tt][r] * scl0 : -INFINITY;
            }
            float ma = max3f(s0[0][0], s0[0][1], s0[0][2]);
            float mb = max3f(s0[0][3], s0[1][0], s0[1][1]);
            float mc = max3f(s0[1][2], s0[1][3], s0[2][0]);
            float md = max3f(s0[2][1], s0[2][2], s0[2][3]);
            float me = max3f(s0[3][0], s0[3][1], s0[3][2]);
            float smax = fmaxf(max3f(ma, mb, mc), max3f(md, me, s0[3][3]));
            smax = fmaxf(smax, __shfl_xor(smax, 16));
            smax = fmaxf(smax, __shfl_xor(smax, 32));
            float mnew = fmaxf(mrow0, smax);
            float msafe = (mnew == -INFINITY) ? 0.f : mnew;
            float alpha = fast_exp2(mrow0 - msafe);
            mrow0 = mnew;
            #pragma unroll
            for (int tt = 0; tt < 4; ++tt)
                #pragma unroll
                for (int r = 0; r < 4; ++r)
                    s0[tt][r] = fast_exp2(s0[tt][r] - msafe);
            float l0 = (s0[0][0] + s0[0][1]) + (s0[0][2] + s0[0][3]);
            float l1 = (s0[1][0] + s0[1][1]) + (s0[1][2] + s0[1][3]);
            float l2 = (s0[2][0] + s0[2][1]) + (s0[2][2] + s0[2][3]);
            float l3 = (s0[3][0] + s0[3][1]) + (s0[3][2] + s0[3][3]);
            float ls = (l0 + l1) + (l2 + l3);
            ls += __shfl_xor(ls, 16);
            ls += __shfl_xor(ls, 32);
            lrow0 = lrow0 * alpha + ls;
            #pragma unroll
            for (int dt = 0; dt < 4; ++dt) out0[dt] *= alpha;
            #pragma unroll
            for (int tt = 0; tt < 4; ++tt) {
                unsigned lo = cvt_pk_bf16(s0[tt][0], s0[tt][1]);
                unsigned hi = cvt_pk_bf16(s0[tt][2], s0[tt][3]);
                int kk = 16 * tt + 4 * lhi;
                *(uint2*)&pw[(l15 * 64 + kk) ^ swz] = make_uint2(lo, hi);
            }
        }
        // ---- group 1 softmax ----
        {
            unsigned long long am = g1 ? amn_ : amp_;
            #pragma unroll
            for (int tt = 0; tt < 4; ++tt) {
                unsigned nib = (unsigned)(am >> (16 * tt + 4 * lhi)) & 0xFu;
                #pragma unroll
                for (int r = 0; r < 4; ++r)
                    s1[tt][r] = ((nib >> r) & 1u) ? s1[tt][r] * scl1 : -INFINITY;
            }
            float ma = max3f(s1[0][0], s1[0][1], s1[0][2]);
            float mb = max3f(s1[0][3], s1[1][0], s1[1][1]);
            float mc = max3f(s1[1][2], s1[1][3], s1[2][0]);
            float md = max3f(s1[2][1], s1[2][2], s1[2][3]);
            float me = max3f(s1[3][0], s1[3][1], s1[3][2]);
            float smax = fmaxf(max3f(ma, mb, mc), max3f(md, me, s1[3][3]));
            smax = fmaxf(smax, __shfl_xor(smax, 16));
            smax = fmaxf(smax, __shfl_xor(smax, 32));
            float mnew = fmaxf(mrow1, smax);
            float msafe = (mnew == -INFINITY) ? 0.f : mnew;
            float alpha = fast_exp2(mrow1 - msafe);
            mrow1 = mnew;
            #pragma unroll
            for (int tt = 0; tt < 4; ++tt)
                #pragma unroll
                for (int r = 0; r < 4; ++r)
                    s1[tt][r] = fast_exp2(s1[tt][r] - msafe);
            float l0 = (s1[0][0] + s1[0][1]) + (s1[0][2] + s1[0][3]);
            float l1 = (s1[1][0] + s1[1][1]) + (s1[1][2] + s1[1][3]);
            float l2 = (s1[2][0] + s1[2][1]) + (s1[2][2] + s1[2][3]);
            float l3 = (s1[3][0] + s1[3][1]) + (s1[3][2] + s1[3][3]);
            float ls = (l0 + l1) + (l2 + l3);
            ls += __shfl_xor(ls, 16);
            ls += __shfl_xor(ls, 32);
            lrow1 = lrow1 * alpha + ls;
            #pragma unroll
            for (int dt = 0; dt < 4; ++dt) out1[dt] *= alpha;
            #pragma unroll
            for (int tt = 0; tt < 4; ++tt) {
                unsigned lo = cvt_pk_bf16(s1[tt][0], s1[tt][1]);
                unsigned hi = cvt_pk_bf16(s1[tt][2], s1[tt][3]);
                int kk = 16 * tt + 4 * lhi;
                *(uint2*)&pw[1024 + ((l15 * 64 + kk) ^ swz)] = make_uint2(lo, hi);
            }
        }
        // ---- PV for both groups (vf resident by now) ----
        s16x8 pa0 = *(const s16x8*)&pw[(l15 * 64 + lhi * 8) ^ swz];
        s16x8 pa1 = *(const s16x8*)&pw[(l15 * 64 + 32 + lhi * 8) ^ swz];
        s16x8 pb0 = *(const s16x8*)&pw[1024 + ((l15 * 64 + lhi * 8) ^ swz)];
        s16x8 pb1 = *(const s16x8*)&pw[1024 + ((l15 * 64 + 32 + lhi * 8) ^ swz)];
        #pragma unroll
        for (int dt = 0; dt < 4; ++dt) {
            out0[dt] = MFMA16(vf[2 * dt], pa0, out0[dt]);
            out0[dt] = MFMA16(vf[2 * dt + 1], pa1, out0[dt]);
            out1[dt] = MFMA16(vf[2 * dt], pb0, out1[dt]);
            out1[dt] = MFMA16(vf[2 * dt + 1], pb1, out1[dt]);
        }
        kp += 4 * 4096;
        vp += 4 * 64;
    }

    // ---- two-pass flash merge (reuse one 18.4 KB LDS buffer) ----
    #pragma unroll
    for (int pass = 0; pass < 2; ++pass) {
        __syncthreads();
        {
            const f32x4* o = pass ? out1 : out0;
            #pragma unroll
            for (int dt = 0; dt < 4; ++dt) *(f32x4*)&comb[w][l][4 * dt] = o[dt];
            comb[w][l][16] = pass ? mrow1 : mrow0;
            comb[w][l][17] = pass ? lrow1 : lrow0;
        }
        __syncthreads();
        if (w == 0) {
            int qv = pass ? qv1 : qv0;
            float n0 = pass ? n01 : n00;
            float M = fmaxf(fmaxf(comb[0][l][16], comb[1][l][16]),
                            fmaxf(comb[2][l][16], comb[3][l][16]));
            if (n0 > 0.f) M = fmaxf(M, 0.f);
            float L = n0 * fast_exp2(0.f - M);
            f32x4 o[4] = {{0,0,0,0},{0,0,0,0},{0,0,0,0},{0,0,0,0}};
            #pragma unroll
            for (int w2 = 0; w2 < 4; ++w2) {
                float a = fast_exp2(comb[w2][l][16] - M);
                L += comb[w2][l][17] * a;
                #pragma unroll
                for (int dt = 0; dt < 4; ++dt)
                    o[dt] += *(const f32x4*)&comb[w2][l][4 * dt] * a;
            }
            float invl = 1.0f / L;
            if (qv <= 1025) {
                if (qv >= 2) {
                    int n = qv - 1;
                    ushort_t* dst = xob + (size_t)(b * SEQ + n) * CH + h * 64 + 4 * lhi;
                    #pragma unroll
                    for (int dt = 0; dt < 4; ++dt) {
                        unsigned lo = cvt_pk_bf16(o[dt][0] * invl, o[dt][1] * invl);
                        unsigned hi = cvt_pk_bf16(o[dt][2] * invl, o[dt][3] * invl);
                        *(uint2*)(dst + 16 * dt) = make_uint2(lo, hi);
                    }
                } else {
                    float* dst = clsf + (size_t)(qv * BATCH + b) * CH + h * 64 + 4 * lhi;
                    #pragma unroll
                    for (int dt = 0; dt < 4; ++dt)
                        #pragma unroll
                        for (int r = 0; r < 4; ++r)
                            dst[16 * dt + r] = o[dt][r] * invl;
                }
            }
        }
    }
}

// ---------------- CLS combine into xob row 0 ----------------
__global__ __launch_bounds__(768) void cls_combine(
    const float* __restrict__ clsf, ushort_t* __restrict__ xob)
{
    int b = blockIdx.x, c = threadIdx.x;
    float v = 0.5f * (clsf[(size_t)b * CH + c] + clsf[(size_t)(BATCH + b) * CH + c]);
    xob[(size_t)b * SEQ * CH + c] = f2bf(v);
}

extern "C" void kernel_launch(void* const* d_in, const int* in_sizes, int n_in,
                              void* d_out, int out_size, void* d_ws, size_t ws_size,
                              hipStream_t stream) {
    const float* x      = (const float*)d_in[0];
    const float* g_info = (const float*)d_in[1];
    const float* w_qkv  = (const float*)d_in[2];
    const float* w_proj = (const float*)d_in[3];
    const float* b_proj = (const float*)d_in[4];
    float* out = (float*)d_out;
    char* ws = (char*)d_ws;

    size_t off = 0;
    auto alloc = [&](size_t bytes) { size_t o = off; off += (bytes + 255) & ~(size_t)255; return o; };
    float*    qf    = (float*)(ws + alloc((size_t)MROWS * CH * 4));
    ushort_t* xb    = (ushort_t*)(ws + alloc((size_t)MROWS * CH * 2));
    ushort_t* wkvT  = (ushort_t*)(ws + alloc((size_t)2 * CH * CH * 2));
    ushort_t* wpT   = (ushort_t*)(ws + alloc((size_t)CH * CH * 2));
    ushort_t* qtb   = (ushort_t*)(ws + alloc((size_t)NBH * NKPAD * 64 * 2));
    ushort_t* kbuf  = (ushort_t*)(ws + alloc((size_t)NBH * NKPAD * 64 * 2));
    ushort_t* vtbuf = (ushort_t*)(ws + alloc((size_t)NBH * NKPAD * 64 * 2));
    ushort_t* xob   = (ushort_t*)(ws + alloc((size_t)MROWS * CH * 2));
    float*    clsf  = (float*)(ws + alloc((size_t)2 * BATCH * CH * 4));
    float*    qsim  = (float*)(ws + alloc((size_t)BATCH * 1024 * 4));
    unsigned char* posm = (unsigned char*)(ws + alloc((size_t)BATCH * 1024));
    unsigned long long* actbits = (unsigned long long*)(ws + alloc((size_t)BATCH * 2 * NTILE * 8));
    float* n0arr = (float*)(ws + alloc((size_t)8 * 4));
    unsigned char* vgrp = (unsigned char*)(ws + alloc((size_t)NKPAD));

    // slab-1 partial reuses d_out (projgemm overwrites it at the end)
    float* qpart = out;

    // fused prep: convx + convT(wkv) + convT(wp) + zeropad
    prep<<<5559, 256, 0, stream>>>(x, xb, w_qkv, wkvT, w_proj, wpT, kbuf, vtbuf, qtb);

    // fused fp32 q GEMM (split-K=2) + bf16 K/V GEMM (r21 config)
    fused_gemms<<<2376, 256, 0, stream>>>(x, w_qkv, qf, qpart, xb, wkvT, kbuf, vtbuf);

    // qmix: q = q0+q1 -> qtb + qsim in one pass
    qmix<<<MROWS, 768, 0, stream>>>(qf, qpart, g_info, qtb, qsim);
    mask_kernel<<<1, 1024, 0, stream>>>(qsim, posm, vgrp, actbits, n0arr);

    // attention (32 queries/block, 4-way KV split, batched loads)
    attn_mfma<<<dim3(NQB, NBH), 256, 0, stream>>>(
        qtb, kbuf, vtbuf, actbits, n0arr, vgrp, posm, xob, clsf);
    cls_combine<<<BATCH, CH, 0, stream>>>(clsf, xob);

    // projection (LDS-staged, XCD-bijective) — overwrites d_out
    projgemm<<<396, 256, 0, stream>>>(xob, wpT, b_proj, out);

    // tail output: g_info[1:]
    hipMemcpyAsync(out + (size_t)MROWS * CH, g_info + 2 * CH, (size_t)2 * CH * sizeof(float),
                   hipMemcpyDeviceToDevice, stream);
}